// Round 1
// baseline (111702.136 us; speedup 1.0000x reference)
//
#include <hip/hip_runtime.h>
#include <hip/hip_bf16.h>
#include <math.h>

// ---------------- problem dims ----------------
#define B_TOT 64
#define T_LEN 2048
#define H_DIM 512
#define G_DIM 2048      // 4H
#define D_EMB 32
#define NCONT 3
#define BOSS_V 50
#define HERO_V 200
#define ZC_TOT 256      // H/2

// ---------------- decomposition ----------------
// 4 clusters x 64 wgs = 256 wgs (1 per CU, forced by LDS usage).
// cluster owns 16 batch elems; wg owns 8 hidden units = 32 gate cols (i,f,g,o interleaved).
#define NCL 4
#define WPC 64
#define BG  16
#define CPW 32
#define HPW 8
#define ZPW 4           // z (head) cols per wg: 256/64
#define NTHR 512

#define HSTR 516        // padded LDS row stride (f32) for 512-length rows: stride%32=4
                        // -> rows rotate banks; 16B-aligned (516*4=2064)

// ---------------- LDS layout (floats) ----------------
#define O_WT   0                        // Wt[lc][k] = W_h[k][gc(lc)]   32x516
#define O_H    (O_WT + CPW*HSTR)        // staged h_{t-1}[b][k]         16x516
#define O_W1   (O_H + BG*HSTR)          // W1t[c4][k] = W1[k][zc0+c4]    4x516
#define O_G    (O_W1 + ZPW*HSTR)        // gate accumulators            16x32
#define O_Z    (O_G + BG*CPW)           // z partials                   16x4
#define O_PRED (O_Z + BG*ZPW)           // pred partials, dbl-buffered  2x16
#define O_CST  (O_PRED + 2*BG)          // c-state                      16x8
#define O_WC   (O_CST + BG*HPW)         // W_i cont rows                3x32
#define O_MISC (O_WC + 3*CPW)           // b1s[4], W2s[4], b2s[1]
#define LDS_F  (O_MISC + 9)
#define LDS_BYTES (LDS_F*4)             // ~110.7 KB -> 1 wg/CU

// ---------------- workspace layout (floats) ----------------
#define WS_BOSSP 0
#define WS_HEROP (WS_BOSSP + BOSS_V*G_DIM)      // 102400
#define WS_HBUF  (WS_HEROP + HERO_V*G_DIM)      // 512000  h_buf[2][64][512]
#define WS_ARR   (WS_HBUF + 2*B_TOT*H_DIM)      // 577536  arrive counters (int), 128B/cluster

// ============ kernel A: fold embeddings through W_i ============
// boss_proj[v][g] = boss_table[v] @ W_i[0:32][g] + b_lstm[g]
// hero_proj[v][g] = hero_table[v] @ W_i[32:64][g]
__global__ __launch_bounds__(256) void proj_tables(
    const float* __restrict__ boss_table, const float* __restrict__ hero_table,
    const float* __restrict__ W_i, const float* __restrict__ b_lstm,
    float* __restrict__ ws) {
  int r = blockIdx.x;
  int c0 = threadIdx.x * 8;
  const float* tab; const float* Wb; float* out; bool useb;
  if (r < BOSS_V) { tab = boss_table + r*D_EMB; Wb = W_i;                 out = ws + WS_BOSSP + r*G_DIM; useb = true; }
  else { int r2 = r - BOSS_V; tab = hero_table + r2*D_EMB; Wb = W_i + D_EMB*G_DIM; out = ws + WS_HEROP + r2*G_DIM; useb = false; }
  float acc[8];
  #pragma unroll
  for (int j = 0; j < 8; ++j) acc[j] = useb ? b_lstm[c0+j] : 0.f;
  for (int e = 0; e < D_EMB; ++e) {
    float te = tab[e];
    const float* wr = Wb + e*G_DIM + c0;
    #pragma unroll
    for (int j = 0; j < 8; ++j) acc[j] = fmaf(te, wr[j], acc[j]);
  }
  #pragma unroll
  for (int j = 0; j < 8; ++j) out[c0+j] = acc[j];
}

// ============ kernel B: persistent LSTM + fused head ============
__global__ __launch_bounds__(NTHR, 1) void rudder_lstm(
    const int* __restrict__ boss_anim, const int* __restrict__ hero_anim,
    const float* __restrict__ continuous,
    const float* __restrict__ W_i, const float* __restrict__ W_h,
    const float* __restrict__ W1, const float* __restrict__ b1,
    const float* __restrict__ W2, const float* __restrict__ b2,
    float* __restrict__ ws, float* __restrict__ out) {
  extern __shared__ float smem[];
  const int tid  = threadIdx.x;
  const int lane = tid & 63;
  const int wg   = blockIdx.x;
  const int cl   = wg & (NCL-1);
  const int wi   = wg >> 2;            // 0..63 within cluster
  const int B0   = cl * BG;
  const int hid0 = wi * HPW;
  const int zc0  = wi * ZPW;

  float* bossp = ws + WS_BOSSP;
  float* herop = ws + WS_HEROP;
  float* hbuf  = ws + WS_HBUF;
  int* arrive  = (int*)(ws + WS_ARR) + cl*32;   // 128B-separated per cluster

  // ---- prologue: stage weights into LDS ----
  for (int i = tid; i < CPW*H_DIM; i += NTHR) {          // W_h slice
    int lc = i & (CPW-1);
    int k  = i >> 5;
    int gc = ((lc >> 3) * H_DIM) + hid0 + (lc & 7);      // gate-interleaved col
    smem[O_WT + lc*HSTR + k] = W_h[k*G_DIM + gc];
  }
  for (int i = tid; i < ZPW*H_DIM; i += NTHR) {          // W1 slice (transposed)
    int c4 = i & 3;
    int k  = i >> 2;
    smem[O_W1 + c4*HSTR + k] = W1[k*ZC_TOT + zc0 + c4];
  }
  if (tid < 3*CPW) {
    int j = tid >> 5, lc = tid & 31;
    int gc = ((lc >> 3) * H_DIM) + hid0 + (lc & 7);
    smem[O_WC + j*CPW + lc] = W_i[(2*D_EMB + j)*G_DIM + gc];
  }
  if (tid < ZPW) { smem[O_MISC + tid] = b1[zc0 + tid]; smem[O_MISC + 4 + tid] = W2[zc0 + tid]; }
  if (tid == 0)  smem[O_MISC + 8] = b2[0];
  if (tid < BG*HPW) smem[O_CST + tid] = 0.f;             // c-state
  __syncthreads();

  for (int t = 0; t <= T_LEN; ++t) {
    const bool lstm = (t < T_LEN);
    const bool head = (t > 0);                 // head for sample t-1 uses staged h_{t-1}

    // [A] xg gather into gate accumulators (no dependence on h -> overlaps spin)
    if (lstm) {
      int e = tid;                             // 512 elems = 16b x 32lc
      int b = e >> 5, lc = e & 31;
      int gc = ((lc >> 3) * H_DIM) + hid0 + (lc & 7);
      int babs = B0 + b;
      int bi = boss_anim[babs*T_LEN + t]; bi = min(max(bi, 0), BOSS_V-1);
      int hj = hero_anim[babs*T_LEN + t]; hj = min(max(hj, 0), HERO_V-1);
      const float* cp = continuous + (size_t)(babs*T_LEN + t)*NCONT;
      float g = bossp[bi*G_DIM + gc] + herop[hj*G_DIM + gc];
      g = fmaf(cp[0], smem[O_WC + 0*CPW + lc], g);
      g = fmaf(cp[1], smem[O_WC + 1*CPW + lc], g);
      g = fmaf(cp[2], smem[O_WC + 2*CPW + lc], g);
      smem[O_G + b*CPW + lc] = g;
    }
    if (head) {
      if (tid < BG*ZPW) smem[O_Z + tid] = smem[O_MISC + (tid & 3)];          // z = b1
      else if (tid < BG*ZPW + BG) smem[O_PRED + ((t-1)&1)*BG + (tid - BG*ZPW)] = 0.f;
    }

    // spin: wait for all cluster wgs to have produced h_{t-1}
    if (t > 0) {
      if (lane == 0) {
        const int target = WPC * t;
        while (__hip_atomic_load(arrive, __ATOMIC_RELAXED, __HIP_MEMORY_SCOPE_AGENT) < target) {}
      }
      __threadfence();   // acquire: invalidate caches so staged h is fresh cross-XCD
    }
    // stage h_{t-1} -> LDS (t=0 reads zeroed buffer parity 1)
    {
      const float* hsrc = hbuf + (size_t)((t+1)&1)*(B_TOT*H_DIM) + (size_t)B0*H_DIM;
      for (int i = tid; i < BG*(H_DIM/4); i += NTHR) {
        int b = i >> 7, kk = (i & 127) * 4;
        float4 v = *(const float4*)(hsrc + b*H_DIM + kk);
        *(float4*)(&smem[O_H + b*HSTR + kk]) = v;
      }
    }
    __syncthreads();  // S1

    // [D1] recurrent partial GEMM: g[b][lc] += sum_k h[b][k] * Wt[lc][k]
    if (lstm) {
      int lc = tid & 31;
      int kq = tid >> 5;                       // 0..15, 32 k each
      float a[BG];
      #pragma unroll
      for (int b = 0; b < BG; ++b) a[b] = 0.f;
      int kbase = kq * 32;
      for (int k4 = 0; k4 < 8; ++k4) {
        int k = kbase + k4*4;
        float4 w = *(const float4*)(&smem[O_WT + lc*HSTR + k]);
        #pragma unroll
        for (int b = 0; b < BG; ++b) {
          float4 hv = *(const float4*)(&smem[O_H + b*HSTR + k]);
          a[b] = fmaf(hv.x, w.x, a[b]);
          a[b] = fmaf(hv.y, w.y, a[b]);
          a[b] = fmaf(hv.z, w.z, a[b]);
          a[b] = fmaf(hv.w, w.w, a[b]);
        }
      }
      #pragma unroll
      for (int b = 0; b < BG; ++b) atomicAdd(&smem[O_G + b*CPW + lc], a[b]);
    }
    // [D2] head partial for h_{t-1}: z[b][c4] += sum_k h[b][k] * W1t[c4][k]
    if (head) {
      int c4 = tid & 3;
      int b  = (tid >> 2) & 15;
      int kq8 = tid >> 6;                      // 0..7, 64 k each
      float acc = 0.f;
      int kb = kq8 * 64;
      for (int k4 = 0; k4 < 16; ++k4) {
        int k = kb + k4*4;
        float4 hv = *(const float4*)(&smem[O_H  + b*HSTR  + k]);
        float4 wv = *(const float4*)(&smem[O_W1 + c4*HSTR + k]);
        acc = fmaf(hv.x, wv.x, acc);
        acc = fmaf(hv.y, wv.y, acc);
        acc = fmaf(hv.z, wv.z, acc);
        acc = fmaf(hv.w, wv.w, acc);
      }
      atomicAdd(&smem[O_Z + b*ZPW + c4], acc);
    }
    __syncthreads();  // S2

    // [E] gates -> state update -> publish h_t
    if (lstm && tid < BG*HPW) {
      int b = tid >> 3, hh = tid & 7;
      float gi = smem[O_G + b*CPW + 0*HPW + hh];
      float gf = smem[O_G + b*CPW + 1*HPW + hh];
      float gg = smem[O_G + b*CPW + 2*HPW + hh];
      float go = smem[O_G + b*CPW + 3*HPW + hh];
      float is = 1.f / (1.f + expf(-gi));
      float fs = 1.f / (1.f + expf(-gf));
      float gt = tanhf(gg);
      float os = 1.f / (1.f + expf(-go));
      float c  = fs * smem[O_CST + tid] + is * gt;
      smem[O_CST + tid] = c;
      float h  = os * tanhf(c);
      hbuf[(size_t)(t&1)*(B_TOT*H_DIM) + (size_t)(B0+b)*H_DIM + hid0 + hh] = h;
    }
    // [F] head finalize: relu(z) @ W2-slice -> per-wg pred partial
    if (head && tid >= 128 && tid < 128 + BG*ZPW) {
      int j = tid - 128;
      int b = j >> 2, c4 = j & 3;
      float z = fmaxf(smem[O_Z + b*ZPW + c4], 0.f);
      atomicAdd(&smem[O_PRED + ((t-1)&1)*BG + b], z * smem[O_MISC + 4 + c4]);
    }
    __syncthreads();  // S3

    if (head && tid >= 64 && tid < 64 + BG) {
      int b = tid - 64;
      float v = smem[O_PRED + ((t-1)&1)*BG + b];
      if (wi == 0) v += smem[O_MISC + 8];      // b2 added exactly once
      atomicAdd(&out[(size_t)(B0+b)*T_LEN + (t-1)], v);
    }
    if (lstm && tid == 0) {
      __threadfence();                         // release: drain h_t to LLC visibility
      __hip_atomic_fetch_add(arrive, 1, __ATOMIC_RELAXED, __HIP_MEMORY_SCOPE_AGENT);
    }
  }
}

// ============ launcher ============
extern "C" void kernel_launch(void* const* d_in, const int* in_sizes, int n_in,
                              void* d_out, int out_size, void* d_ws, size_t ws_size,
                              hipStream_t stream) {
  const int*   boss_anim  = (const int*)d_in[0];
  const int*   hero_anim  = (const int*)d_in[1];
  const float* continuous = (const float*)d_in[2];
  const float* boss_table = (const float*)d_in[3];
  const float* hero_table = (const float*)d_in[4];
  const float* W_i    = (const float*)d_in[5];
  const float* W_h    = (const float*)d_in[6];
  const float* b_lstm = (const float*)d_in[7];
  const float* W1     = (const float*)d_in[8];
  const float* b1     = (const float*)d_in[9];
  const float* W2     = (const float*)d_in[10];
  const float* b2     = (const float*)d_in[11];
  float* ws  = (float*)d_ws;
  float* out = (float*)d_out;

  (void)hipFuncSetAttribute((const void*)rudder_lstm,
                            hipFuncAttributeMaxDynamicSharedMemorySize, LDS_BYTES);

  // zero output (atomicAdd accumulation target) and h_buf + arrive counters
  hipMemsetAsync(out, 0, (size_t)B_TOT*T_LEN*sizeof(float), stream);
  hipMemsetAsync(ws + WS_HBUF, 0, (size_t)(2*B_TOT*H_DIM + 128)*sizeof(float), stream);

  proj_tables<<<BOSS_V + HERO_V, 256, 0, stream>>>(boss_table, hero_table, W_i, b_lstm, ws);
  rudder_lstm<<<NCL*WPC, NTHR, LDS_BYTES, stream>>>(boss_anim, hero_anim, continuous,
      W_i, W_h, W1, b1, W2, b2, ws, out);
}

// Round 2
// 46974.631 us; speedup vs baseline: 2.3779x; 2.3779x over previous
//
#include <hip/hip_runtime.h>
#include <hip/hip_bf16.h>
#include <math.h>

// ---------------- problem dims ----------------
#define B_TOT 64
#define T_LEN 2048
#define H_DIM 512
#define G_DIM 2048      // 4H
#define D_EMB 32
#define NCONT 3
#define BOSS_V 50
#define HERO_V 200
#define ZC_TOT 256      // H/2

// ---------------- decomposition ----------------
// 4 clusters x 64 wgs = 256 wgs (1 per CU, forced by LDS usage).
// cluster owns 16 batch elems; wg owns 8 hidden units = 32 gate cols (i,f,g,o interleaved).
#define NCL 4
#define WPC 64
#define BG  16
#define CPW 32
#define HPW 8
#define ZPW 4           // z (head) cols per wg: 256/64
#define NTHR 512

#define HSTR 516        // padded LDS row stride (f32)

// ---------------- LDS layout (floats) ----------------
#define O_WT   0                        // Wt[lc][k] = W_h[k][gc(lc)]   32x516
#define O_H    (O_WT + CPW*HSTR)        // staged h_{t-1}[b][k]         16x516
#define O_W1   (O_H + BG*HSTR)          // W1t[c4][k] = W1[k][zc0+c4]    4x516
#define O_G    (O_W1 + ZPW*HSTR)        // gate accumulators            16x32
#define O_Z    (O_G + BG*CPW)           // z partials                   16x4
#define O_PRED (O_Z + BG*ZPW)           // pred partials, dbl-buffered  2x16
#define O_CST  (O_PRED + 2*BG)          // c-state                      16x8
#define O_WC   (O_CST + BG*HPW)         // W_i cont rows                3x32
#define O_MISC (O_WC + 3*CPW)           // b1s[4], W2s[4], b2s[1]
#define LDS_F  (O_MISC + 9)
#define LDS_BYTES (LDS_F*4)             // ~110.7 KB -> 1 wg/CU

// ---------------- workspace layout (floats) ----------------
#define WS_BOSSP 0
#define WS_HEROP (WS_BOSSP + BOSS_V*G_DIM)      // 102400
#define WS_HBUF  (WS_HEROP + HERO_V*G_DIM)      // 512000  h_buf[2][64][512]
#define WS_FLG   (WS_HBUF + 2*B_TOT*H_DIM)      // 577536  flags[4][64] (int)

// fast activations: v_exp_f32 (2^x) + v_rcp_f32, ~1ulp each.
__device__ __forceinline__ float fsig(float x) {
  return __builtin_amdgcn_rcpf(1.f + __builtin_amdgcn_exp2f(-1.44269504f * x));
}
__device__ __forceinline__ float ftanh(float x) {
  float e = __builtin_amdgcn_exp2f(2.88539008f * x);   // e^{2x}
  return 1.f - 2.f * __builtin_amdgcn_rcpf(e + 1.f);   // +inf -> 1, 0 -> -1
}

// ============ kernel A: fold embeddings through W_i ============
__global__ __launch_bounds__(256) void proj_tables(
    const float* __restrict__ boss_table, const float* __restrict__ hero_table,
    const float* __restrict__ W_i, const float* __restrict__ b_lstm,
    float* __restrict__ ws) {
  int r = blockIdx.x;
  int c0 = threadIdx.x * 8;
  const float* tab; const float* Wb; float* out; bool useb;
  if (r < BOSS_V) { tab = boss_table + r*D_EMB; Wb = W_i;                 out = ws + WS_BOSSP + r*G_DIM; useb = true; }
  else { int r2 = r - BOSS_V; tab = hero_table + r2*D_EMB; Wb = W_i + D_EMB*G_DIM; out = ws + WS_HEROP + r2*G_DIM; useb = false; }
  float acc[8];
  #pragma unroll
  for (int j = 0; j < 8; ++j) acc[j] = useb ? b_lstm[c0+j] : 0.f;
  for (int e = 0; e < D_EMB; ++e) {
    float te = tab[e];
    const float* wr = Wb + e*G_DIM + c0;
    #pragma unroll
    for (int j = 0; j < 8; ++j) acc[j] = fmaf(te, wr[j], acc[j]);
  }
  #pragma unroll
  for (int j = 0; j < 8; ++j) out[c0+j] = acc[j];
}

// ============ kernel B: persistent LSTM + fused head ============
__global__ __launch_bounds__(NTHR, 1) void rudder_lstm(
    const int* __restrict__ boss_anim, const int* __restrict__ hero_anim,
    const float* __restrict__ continuous,
    const float* __restrict__ W_i, const float* __restrict__ W_h,
    const float* __restrict__ W1, const float* __restrict__ b1,
    const float* __restrict__ W2, const float* __restrict__ b2,
    float* __restrict__ ws, float* __restrict__ out) {
  extern __shared__ float smem[];
  const int tid  = threadIdx.x;
  const int wg   = blockIdx.x;
  const int cl   = wg & (NCL-1);
  const int wi   = wg >> 2;            // 0..63 within cluster
  const int B0   = cl * BG;
  const int hid0 = wi * HPW;
  const int zc0  = wi * ZPW;

  float* bossp = ws + WS_BOSSP;
  float* herop = ws + WS_HEROP;
  float* hbuf  = ws + WS_HBUF;
  int* flags_cl = (int*)(ws + WS_FLG) + cl*WPC;   // 64 flags, 1 writer each

  // ---- prologue: stage weights into LDS ----
  for (int i = tid; i < CPW*H_DIM; i += NTHR) {          // W_h slice
    int lc = i & (CPW-1);
    int k  = i >> 5;
    int gc = ((lc >> 3) * H_DIM) + hid0 + (lc & 7);      // gate-interleaved col
    smem[O_WT + lc*HSTR + k] = W_h[k*G_DIM + gc];
  }
  for (int i = tid; i < ZPW*H_DIM; i += NTHR) {          // W1 slice (transposed)
    int c4 = i & 3;
    int k  = i >> 2;
    smem[O_W1 + c4*HSTR + k] = W1[k*ZC_TOT + zc0 + c4];
  }
  if (tid < 3*CPW) {
    int j = tid >> 5, lc = tid & 31;
    int gc = ((lc >> 3) * H_DIM) + hid0 + (lc & 7);
    smem[O_WC + j*CPW + lc] = W_i[(2*D_EMB + j)*G_DIM + gc];
  }
  if (tid < ZPW) { smem[O_MISC + tid] = b1[zc0 + tid]; smem[O_MISC + 4 + tid] = W2[zc0 + tid]; }
  if (tid == 0)  smem[O_MISC + 8] = b2[0];
  if (tid < BG*HPW) smem[O_CST + tid] = 0.f;             // c-state
  __syncthreads();

  for (int t = 0; t <= T_LEN; ++t) {
    const bool lstm = (t < T_LEN);
    const bool head = (t > 0);                 // head for sample t-1 uses staged h_{t-1}

    // [A] xg gather into gate accumulators (no dependence on h -> overlaps peers)
    if (lstm) {
      int e = tid;                             // 512 elems = 16b x 32lc
      int b = e >> 5, lc = e & 31;
      int gc = ((lc >> 3) * H_DIM) + hid0 + (lc & 7);
      int babs = B0 + b;
      int bi = boss_anim[babs*T_LEN + t]; bi = min(max(bi, 0), BOSS_V-1);
      int hj = hero_anim[babs*T_LEN + t]; hj = min(max(hj, 0), HERO_V-1);
      const float* cp = continuous + (size_t)(babs*T_LEN + t)*NCONT;
      float g = bossp[bi*G_DIM + gc] + herop[hj*G_DIM + gc];
      g = fmaf(cp[0], smem[O_WC + 0*CPW + lc], g);
      g = fmaf(cp[1], smem[O_WC + 1*CPW + lc], g);
      g = fmaf(cp[2], smem[O_WC + 2*CPW + lc], g);
      smem[O_G + b*CPW + lc] = g;
    }
    if (head) {
      if (tid < BG*ZPW) smem[O_Z + tid] = smem[O_MISC + (tid & 3)];          // z = b1
      else if (tid < BG*ZPW + BG) smem[O_PRED + ((t-1)&1)*BG + (tid - BG*ZPW)] = 0.f;
    }

    // spin: wave 0's 64 lanes poll the cluster's 64 flags (sc1 loads, no RMW,
    // no cache-maintenance fence — relaxed agent atomics are LLC-coherent).
    if (t > 0) {
      if (tid < 64) {
        int v;
        do {
          v = __hip_atomic_load(&flags_cl[tid], __ATOMIC_RELAXED, __HIP_MEMORY_SCOPE_AGENT);
        } while (__any(v < t));
      }
      __syncthreads();  // S0: release the staging waves
    }
    // stage h_{t-1} -> LDS via sc1 loads (bypass possibly-stale local L2)
    {
      const float* hsrc = hbuf + (size_t)((t+1)&1)*(B_TOT*H_DIM) + (size_t)B0*H_DIM;
      for (int i = tid; i < BG*H_DIM; i += NTHR) {       // 16 dwords per thread
        int b = i >> 9, kk = i & 511;
        smem[O_H + b*HSTR + kk] =
            __hip_atomic_load(hsrc + b*H_DIM + kk, __ATOMIC_RELAXED, __HIP_MEMORY_SCOPE_AGENT);
      }
    }
    __syncthreads();  // S1

    // [D1] recurrent partial GEMM: g[b][lc] += sum_k h[b][k] * Wt[lc][k]
    if (lstm) {
      int lc = tid & 31;
      int kq = tid >> 5;                       // 0..15, 32 k each
      float a[BG];
      #pragma unroll
      for (int b = 0; b < BG; ++b) a[b] = 0.f;
      int kbase = kq * 32;
      for (int k4 = 0; k4 < 8; ++k4) {
        int k = kbase + k4*4;
        float4 w = *(const float4*)(&smem[O_WT + lc*HSTR + k]);
        #pragma unroll
        for (int b = 0; b < BG; ++b) {
          float4 hv = *(const float4*)(&smem[O_H + b*HSTR + k]);
          a[b] = fmaf(hv.x, w.x, a[b]);
          a[b] = fmaf(hv.y, w.y, a[b]);
          a[b] = fmaf(hv.z, w.z, a[b]);
          a[b] = fmaf(hv.w, w.w, a[b]);
        }
      }
      #pragma unroll
      for (int b = 0; b < BG; ++b) atomicAdd(&smem[O_G + b*CPW + lc], a[b]);
    }
    // [D2] head partial for h_{t-1}: z[b][c4] += sum_k h[b][k] * W1t[c4][k]
    if (head) {
      int c4 = tid & 3;
      int b  = (tid >> 2) & 15;
      int kq8 = tid >> 6;                      // 0..7, 64 k each
      float acc = 0.f;
      int kb = kq8 * 64;
      for (int k4 = 0; k4 < 16; ++k4) {
        int k = kb + k4*4;
        float4 hv = *(const float4*)(&smem[O_H  + b*HSTR  + k]);
        float4 wv = *(const float4*)(&smem[O_W1 + c4*HSTR + k]);
        acc = fmaf(hv.x, wv.x, acc);
        acc = fmaf(hv.y, wv.y, acc);
        acc = fmaf(hv.z, wv.z, acc);
        acc = fmaf(hv.w, wv.w, acc);
      }
      atomicAdd(&smem[O_Z + b*ZPW + c4], acc);
    }
    __syncthreads();  // S2

    // [E] gates -> state update -> publish h_t (wave 0 only, so one wave's
    // vmcnt covers all h stores before the flag store)
    if (lstm && tid < 64) {
      #pragma unroll
      for (int half = 0; half < 2; ++half) {
        int cell = tid + half*64;              // 0..127 = 16b x 8hh
        int b = cell >> 3, hh = cell & 7;
        float gi = smem[O_G + b*CPW + 0*HPW + hh];
        float gf = smem[O_G + b*CPW + 1*HPW + hh];
        float gg = smem[O_G + b*CPW + 2*HPW + hh];
        float go = smem[O_G + b*CPW + 3*HPW + hh];
        float is = fsig(gi);
        float fs = fsig(gf);
        float gt = ftanh(gg);
        float os = fsig(go);
        float c  = fs * smem[O_CST + cell] + is * gt;
        smem[O_CST + cell] = c;
        float h  = os * ftanh(c);
        __hip_atomic_store(
            hbuf + (size_t)(t&1)*(B_TOT*H_DIM) + (size_t)(B0+b)*H_DIM + hid0 + hh,
            h, __ATOMIC_RELAXED, __HIP_MEMORY_SCOPE_AGENT);
      }
      asm volatile("s_waitcnt vmcnt(0)" ::: "memory");  // release: h (sc1) -> LLC done
      if (tid == 0)
        __hip_atomic_store(&flags_cl[wi], t + 1, __ATOMIC_RELAXED, __HIP_MEMORY_SCOPE_AGENT);
    }
    // [F] head finalize: relu(z) @ W2-slice -> per-wg pred partial (wave 2)
    if (head && tid >= 128 && tid < 128 + BG*ZPW) {
      int j = tid - 128;
      int b = j >> 2, c4 = j & 3;
      float z = fmaxf(smem[O_Z + b*ZPW + c4], 0.f);
      atomicAdd(&smem[O_PRED + ((t-1)&1)*BG + b], z * smem[O_MISC + 4 + c4]);
    }
    __syncthreads();  // S3

    if (head && tid >= 64 && tid < 64 + BG) {
      int b = tid - 64;
      float v = smem[O_PRED + ((t-1)&1)*BG + b];
      if (wi == 0) v += smem[O_MISC + 8];      // b2 added exactly once
      atomicAdd(&out[(size_t)(B0+b)*T_LEN + (t-1)], v);
    }
  }
}

// ============ launcher ============
extern "C" void kernel_launch(void* const* d_in, const int* in_sizes, int n_in,
                              void* d_out, int out_size, void* d_ws, size_t ws_size,
                              hipStream_t stream) {
  const int*   boss_anim  = (const int*)d_in[0];
  const int*   hero_anim  = (const int*)d_in[1];
  const float* continuous = (const float*)d_in[2];
  const float* boss_table = (const float*)d_in[3];
  const float* hero_table = (const float*)d_in[4];
  const float* W_i    = (const float*)d_in[5];
  const float* W_h    = (const float*)d_in[6];
  const float* b_lstm = (const float*)d_in[7];
  const float* W1     = (const float*)d_in[8];
  const float* b1     = (const float*)d_in[9];
  const float* W2     = (const float*)d_in[10];
  const float* b2     = (const float*)d_in[11];
  float* ws  = (float*)d_ws;
  float* out = (float*)d_out;

  (void)hipFuncSetAttribute((const void*)rudder_lstm,
                            hipFuncAttributeMaxDynamicSharedMemorySize, LDS_BYTES);

  // zero output (atomicAdd target), h_buf (both parities), and flags
  hipMemsetAsync(out, 0, (size_t)B_TOT*T_LEN*sizeof(float), stream);
  hipMemsetAsync(ws + WS_HBUF, 0, (size_t)(2*B_TOT*H_DIM + NCL*WPC)*sizeof(float), stream);

  proj_tables<<<BOSS_V + HERO_V, 256, 0, stream>>>(boss_table, hero_table, W_i, b_lstm, ws);
  rudder_lstm<<<NCL*WPC, NTHR, LDS_BYTES, stream>>>(boss_anim, hero_anim, continuous,
      W_i, W_h, W1, b1, W2, b2, ws, out);
}

// Round 3
// 14037.827 us; speedup vs baseline: 7.9572x; 3.3463x over previous
//
#include <hip/hip_runtime.h>
#include <hip/hip_bf16.h>
#include <math.h>

// ---------------- problem dims ----------------
#define B_TOT 64
#define T_LEN 2048
#define H_DIM 512
#define G_DIM 2048      // 4H
#define D_EMB 32
#define NCONT 3
#define BOSS_V 50
#define HERO_V 200
#define ZC_TOT 256      // H/2

// ---------------- decomposition ----------------
// 4 clusters x 16 wgs = 64 wgs (1 per CU). Cluster owns 16 batch elems.
// wg owns 32 hidden units = 128 gate cols (+16 z cols). 8 waves/wg.
// Wave w computes C rows c=16w..16w+15; colmap: c=16w+r, r=4*q+j ->
// gate q, hh = 4w+j, global gate col = q*512 + hid0 + 4w + j.
#define NCL 4
#define WPC 16
#define BG  16
#define NTHR 512

// ---------------- LDS layout (bytes) ----------------
// W rows: 144 rows (128 gate cols + 16 z cols) x 512 f16 = 1024 B/row, XOR-swizzled
#define O_W    0
#define O_SCR  (144*1024)               // D2 partials: 8 waves x 16b x 16m f32 = 8 KB
#define LDS_BYTES (O_SCR + 8*1024)      // 155648 < 160 KiB

// ---------------- workspace layout (bytes) ----------------
#define WSB_BOSSP 0                      // f32 [50][2048]   409600
#define WSB_HEROP 409600                 // f32 [200][2048] 1638400
#define WSB_HBUF  2048000                // f16 [2][64][512] 131072
#define WSB_FLG   2179072                // int [4][16] (64 B per cluster)
// total 2179328 B  (< 2310656 proven available)

typedef _Float16 half8 __attribute__((ext_vector_type(8)));
typedef float f32x4 __attribute__((ext_vector_type(4)));
typedef unsigned int u32x4 __attribute__((ext_vector_type(4)));
typedef unsigned int u32x2 __attribute__((ext_vector_type(2)));

__device__ __forceinline__ half8 as_half8(u32x4 v) { union { u32x4 u; half8 h; } x; x.u = v; return x.h; }

__device__ __forceinline__ float fsig(float x) {
  return __builtin_amdgcn_rcpf(1.f + __builtin_amdgcn_exp2f(-1.44269504f * x));
}
__device__ __forceinline__ float ftanh(float x) {
  float e = __builtin_amdgcn_exp2f(2.88539008f * x);   // e^{2x}
  return 1.f - 2.f * __builtin_amdgcn_rcpf(e + 1.f);
}

#define GLOAD(dst, a, off) \
  asm volatile("global_load_dwordx4 %0, %1, off offset:" #off " sc0 sc1" : "=v"(dst) : "v"(a))

// ============ kernel A: fold embeddings through W_i (f32, unchanged) ============
__global__ __launch_bounds__(256) void proj_tables(
    const float* __restrict__ boss_table, const float* __restrict__ hero_table,
    const float* __restrict__ W_i, const float* __restrict__ b_lstm,
    float* __restrict__ ws) {
  int r = blockIdx.x;
  int c0 = threadIdx.x * 8;
  const float* tab; const float* Wb; float* out; bool useb;
  if (r < BOSS_V) { tab = boss_table + r*D_EMB; Wb = W_i;                 out = ws + r*G_DIM; useb = true; }
  else { int r2 = r - BOSS_V; tab = hero_table + r2*D_EMB; Wb = W_i + D_EMB*G_DIM; out = ws + (WSB_HEROP/4) + r2*G_DIM; useb = false; }
  float acc[8];
  #pragma unroll
  for (int j = 0; j < 8; ++j) acc[j] = useb ? b_lstm[c0+j] : 0.f;
  for (int e = 0; e < D_EMB; ++e) {
    float te = tab[e];
    const float* wr = Wb + e*G_DIM + c0;
    #pragma unroll
    for (int j = 0; j < 8; ++j) acc[j] = fmaf(te, wr[j], acc[j]);
  }
  #pragma unroll
  for (int j = 0; j < 8; ++j) out[c0+j] = acc[j];
}

// ============ kernel B: persistent MFMA LSTM + fused head ============
__global__ __launch_bounds__(NTHR, 1) void rudder_lstm(
    const int* __restrict__ boss_anim, const int* __restrict__ hero_anim,
    const float* __restrict__ continuous,
    const float* __restrict__ W_i, const float* __restrict__ W_h,
    const float* __restrict__ W1, const float* __restrict__ b1,
    const float* __restrict__ W2, const float* __restrict__ b2,
    char* __restrict__ wsb, float* __restrict__ out) {
  extern __shared__ char smem[];
  const int tid  = threadIdx.x;
  const int wave = tid >> 6;
  const int lane = tid & 63;
  const int b    = lane & 15;       // batch (B/C/D col), also A row for D1/D2
  const int q    = lane >> 4;       // k-group / gate group
  const int rb7  = lane & 7;        // swizzle key
  const int wg   = blockIdx.x;
  const int cl   = wg & (NCL-1);
  const int wi   = wg >> 2;         // 0..15 within cluster
  const int B0   = cl * BG;
  const int hid0 = wi * 32;
  const int zc0  = wi * 16;

  const float* bossp = (const float*)(wsb + WSB_BOSSP);
  const float* herop = (const float*)(wsb + WSB_HEROP);
  char* hb = wsb + WSB_HBUF;
  int* flags_cl = (int*)(wsb + WSB_FLG) + cl*16;

  // ---- prologue: W_h slice (rows 0..127) + W1 slice (rows 128..143) -> LDS f16, swizzled ----
  for (int idx = tid; idx < 144*64; idx += NTHR) {
    int c = idx >> 6, s = idx & 63;
    int r = c & 15;
    const float* src; int stride;
    if (c < 128) {
      int qg = r >> 2, j = r & 3, wb = c >> 4;
      src = W_h + qg*512 + hid0 + wb*4 + j;  stride = G_DIM;
    } else {
      src = W1 + zc0 + r;                    stride = ZC_TOT;
    }
    union { _Float16 h[8]; u32x4 u; } tmp;
    int k0 = s * 8;
    #pragma unroll
    for (int kk = 0; kk < 8; ++kk) tmp.h[kk] = (_Float16)src[(size_t)(k0+kk)*stride];
    *(u32x4*)(smem + O_W + c*1024 + ((s ^ (c&7)) << 4)) = tmp.u;
  }

  // per-lane constants
  const int gcol0 = q*512 + hid0 + 4*wave;             // xg float4 base col
  float4 Wc0 = *(const float4*)(W_i + (size_t)(2*D_EMB+0)*G_DIM + gcol0);
  float4 Wc1 = *(const float4*)(W_i + (size_t)(2*D_EMB+1)*G_DIM + gcol0);
  float4 Wc2 = *(const float4*)(W_i + (size_t)(2*D_EMB+2)*G_DIM + gcol0);
  float4 b1v = *(const float4*)(b1 + zc0 + q*4);
  float4 W2v = *(const float4*)(W2 + zc0 + q*4);
  float b2v = b2[0];
  float cst0 = 0.f, cst1 = 0.f, cst2 = 0.f, cst3 = 0.f; // c-state (lanes q==0)
  __syncthreads();

  for (int t = 0; t <= T_LEN; ++t) {
    const bool lstm = (t < T_LEN);
    const bool head = (t > 0);

    // [A] xg init (independent of h) — issue before the spin
    f32x4 acc = {0.f, 0.f, 0.f, 0.f};
    if (lstm) {
      const int row = (B0 + b)*T_LEN + t;
      int bi = min(max(boss_anim[row], 0), BOSS_V-1);
      int hj = min(max(hero_anim[row], 0), HERO_V-1);
      float4 bp = *(const float4*)(bossp + (size_t)bi*G_DIM + gcol0);
      float4 hp = *(const float4*)(herop + (size_t)hj*G_DIM + gcol0);
      const float* cp = continuous + (size_t)row*NCONT;
      float cc0 = cp[0], cc1 = cp[1], cc2 = cp[2];
      acc[0] = bp.x + hp.x + cc0*Wc0.x + cc1*Wc1.x + cc2*Wc2.x;
      acc[1] = bp.y + hp.y + cc0*Wc0.y + cc1*Wc1.y + cc2*Wc2.y;
      acc[2] = bp.z + hp.z + cc0*Wc0.z + cc1*Wc1.z + cc2*Wc2.z;
      acc[3] = bp.w + hp.w + cc0*Wc0.w + cc1*Wc1.w + cc2*Wc2.w;
    }

    // spin: wave0 polls the cluster's 16 flags (single-writer each, no RMW)
    if (t > 0 && wave == 0) {
      unsigned long long fa = (unsigned long long)(flags_cl + (lane & 15));
      int v;
      do {
        asm volatile("global_load_dword %0, %1, off sc0 sc1\n\ts_waitcnt vmcnt(0)"
                     : "=v"(v) : "v"(fa) : "memory");
      } while (__any(v < t));
    }
    __syncthreads();  // SB0 (also protects D2 scratch WAR from previous iter)

    // B-fragment loads: h_{t-1} f16 direct LLC->registers (coherent, bypass L1/L2)
    u32x4 B[16], B2a, B2b;
    {
      unsigned long long ha = (unsigned long long)(hb + ((t+1)&1)*65536) + (unsigned)((B0+b)*1024 + q*16);
      unsigned long long h2 = ha + (unsigned)(wave*128);
      GLOAD(B[0],  ha,   0); GLOAD(B[1],  ha,  64); GLOAD(B[2],  ha, 128); GLOAD(B[3],  ha, 192);
      GLOAD(B[4],  ha, 256); GLOAD(B[5],  ha, 320); GLOAD(B[6],  ha, 384); GLOAD(B[7],  ha, 448);
      GLOAD(B[8],  ha, 512); GLOAD(B[9],  ha, 576); GLOAD(B[10], ha, 640); GLOAD(B[11], ha, 704);
      GLOAD(B[12], ha, 768); GLOAD(B[13], ha, 832); GLOAD(B[14], ha, 896); GLOAD(B[15], ha, 960);
      GLOAD(B2a, h2, 0); GLOAD(B2b, h2, 64);
      asm volatile("s_waitcnt vmcnt(0)" ::: "memory");
      __builtin_amdgcn_sched_barrier(0);
    }

    // [D1] recurrent GEMM: 16 MFMA over K=512
    if (lstm) {
      const char* arow = smem + O_W + (16*wave + b)*1024;
      #pragma unroll
      for (int s = 0; s < 16; ++s) {
        u32x4 a = *(const u32x4*)(arow + (((s*4 + q) ^ rb7) << 4));
        acc = __builtin_amdgcn_mfma_f32_16x16x32_f16(as_half8(a), as_half8(B[s]), acc, 0, 0, 0);
      }
      // gates: lane group q holds gate q for hh=4*wave+j; gather via shfl_xor
      float gi0 = acc[0], gi1 = acc[1], gi2 = acc[2], gi3 = acc[3];
      float gf0 = __shfl_xor(gi0, 16), gf1 = __shfl_xor(gi1, 16), gf2 = __shfl_xor(gi2, 16), gf3 = __shfl_xor(gi3, 16);
      float gg0 = __shfl_xor(gi0, 32), gg1 = __shfl_xor(gi1, 32), gg2 = __shfl_xor(gi2, 32), gg3 = __shfl_xor(gi3, 32);
      float go0 = __shfl_xor(gi0, 48), go1 = __shfl_xor(gi1, 48), go2 = __shfl_xor(gi2, 48), go3 = __shfl_xor(gi3, 48);
      if (q == 0) {
        union { _Float16 h[4]; u32x2 u; } P;
        cst0 = fsig(gf0)*cst0 + fsig(gi0)*ftanh(gg0); P.h[0] = (_Float16)(fsig(go0)*ftanh(cst0));
        cst1 = fsig(gf1)*cst1 + fsig(gi1)*ftanh(gg1); P.h[1] = (_Float16)(fsig(go1)*ftanh(cst1));
        cst2 = fsig(gf2)*cst2 + fsig(gi2)*ftanh(gg2); P.h[2] = (_Float16)(fsig(go2)*ftanh(cst2));
        cst3 = fsig(gf3)*cst3 + fsig(gi3)*ftanh(gg3); P.h[3] = (_Float16)(fsig(go3)*ftanh(cst3));
        unsigned long long pa = (unsigned long long)(hb + (t&1)*65536)
                              + (unsigned)(((B0 + lane)*512 + hid0 + 4*wave)*2);
        asm volatile("global_store_dwordx2 %0, %1, off sc0 sc1" :: "v"(pa), "v"(P.u) : "memory");
      }
    }
    asm volatile("s_waitcnt vmcnt(0)" ::: "memory");  // publish acks complete
    __syncthreads();  // SB1
    if (lstm && tid == 0) {
      unsigned long long fa = (unsigned long long)(flags_cl + wi);
      int val = t + 1;
      asm volatile("global_store_dword %0, %1, off sc0 sc1" :: "v"(fa), "v"(val) : "memory");
    }

    // [D2] head for t-1 (off inter-wg critical path): K-split MFMA, partials -> LDS
    if (head) {
      f32x4 z = {0.f, 0.f, 0.f, 0.f};
      const char* arow2 = smem + O_W + (128 + b)*1024;
      {
        int s = 2*wave;
        u32x4 a = *(const u32x4*)(arow2 + (((s*4 + q) ^ rb7) << 4));
        z = __builtin_amdgcn_mfma_f32_16x16x32_f16(as_half8(a), as_half8(B2a), z, 0, 0, 0);
        s = 2*wave + 1;
        u32x4 a2 = *(const u32x4*)(arow2 + (((s*4 + q) ^ rb7) << 4));
        z = __builtin_amdgcn_mfma_f32_16x16x32_f16(as_half8(a2), as_half8(B2b), z, 0, 0, 0);
      }
      *(f32x4*)(smem + O_SCR + wave*1024 + b*64 + q*16) = z;
    }
    __syncthreads();  // SB2
    if (head && wave == 0) {
      float z0 = 0.f, z1 = 0.f, z2 = 0.f, z3 = 0.f;
      #pragma unroll
      for (int w2 = 0; w2 < 8; ++w2) {
        f32x4 p = *(const f32x4*)(smem + O_SCR + w2*1024 + b*64 + q*16);
        z0 += p[0]; z1 += p[1]; z2 += p[2]; z3 += p[3];
      }
      float s = fmaxf(z0 + b1v.x, 0.f)*W2v.x + fmaxf(z1 + b1v.y, 0.f)*W2v.y
              + fmaxf(z2 + b1v.z, 0.f)*W2v.z + fmaxf(z3 + b1v.w, 0.f)*W2v.w;
      s += __shfl_xor(s, 16);
      s += __shfl_xor(s, 32);
      if (q == 0) {
        if (wi == 0) s += b2v;
        atomicAdd(out + (size_t)(B0 + lane)*T_LEN + (t-1), s);
      }
    }
  }
}

// ============ launcher ============
extern "C" void kernel_launch(void* const* d_in, const int* in_sizes, int n_in,
                              void* d_out, int out_size, void* d_ws, size_t ws_size,
                              hipStream_t stream) {
  const int*   boss_anim  = (const int*)d_in[0];
  const int*   hero_anim  = (const int*)d_in[1];
  const float* continuous = (const float*)d_in[2];
  const float* boss_table = (const float*)d_in[3];
  const float* hero_table = (const float*)d_in[4];
  const float* W_i    = (const float*)d_in[5];
  const float* W_h    = (const float*)d_in[6];
  const float* b_lstm = (const float*)d_in[7];
  const float* W1     = (const float*)d_in[8];
  const float* b1     = (const float*)d_in[9];
  const float* W2     = (const float*)d_in[10];
  const float* b2     = (const float*)d_in[11];
  char*  wsb = (char*)d_ws;
  float* out = (float*)d_out;

  (void)hipFuncSetAttribute((const void*)rudder_lstm,
                            hipFuncAttributeMaxDynamicSharedMemorySize, LDS_BYTES);

  // zero output (atomicAdd target) + hbuf (both parities) + flags
  hipMemsetAsync(out, 0, (size_t)B_TOT*T_LEN*sizeof(float), stream);
  hipMemsetAsync(wsb + WSB_HBUF, 0, 131072 + 256, stream);

  proj_tables<<<BOSS_V + HERO_V, 256, 0, stream>>>(boss_table, hero_table, W_i, b_lstm, (float*)wsb);
  rudder_lstm<<<NCL*WPC, NTHR, LDS_BYTES, stream>>>(boss_anim, hero_anim, continuous,
      W_i, W_h, W1, b1, W2, b2, wsb, out);
}

// Round 4
// 7356.998 us; speedup vs baseline: 15.1831x; 1.9081x over previous
//
#include <hip/hip_runtime.h>
#include <hip/hip_bf16.h>
#include <math.h>

// ---------------- problem dims ----------------
#define B_TOT 64
#define T_LEN 2048
#define H_DIM 512
#define G_DIM 2048      // 4H
#define D_EMB 32
#define NCONT 3
#define BOSS_V 50
#define HERO_V 200
#define ZC_TOT 256      // H/2

// ---------------- decomposition ----------------
// 4 clusters x 16 wgs = 64 wgs (1 per CU). Cluster owns 16 batch elems.
// wg owns 32 hidden units = 128 gate cols (+16 z cols). 4 waves x 64 = 256 thr.
// Gate-row map: R = hh_local*4 + g  (g = gate i,f,g,o).
// Wave w, tile tau (0/1), lane (q,b):
//   C/D reg j  -> R = 32w+16tau+4q+j -> gate j, hh_local = 8w+4tau+q
//   A-frag row -> R = 32w+16tau+b    -> W_h col (b&3)*512 + hid0+8w+4tau+(b>>2)
// => all 4 gates of one (hh,b) land in ONE lane's 4 regs: no shfl for gates.
#define NCL 4
#define WPC 16
#define BG  16
#define NTHR 256

// ---------------- workspace layout (bytes) ----------------
#define WSB_BOSSP 0                               // f32 [50][2048] PACKED p=hh*4+g
#define WSB_HEROP (BOSS_V*G_DIM*4)                // f32 [200][2048] packed, 409600
#define WSB_HBUF  (WSB_HEROP + HERO_V*G_DIM*4)    // f16 [2][64][512] @ 2048000
#define WSB_FLG   (WSB_HBUF + 2*B_TOT*H_DIM*2)    // int [4][16]      @ 2179072

typedef _Float16 half8 __attribute__((ext_vector_type(8)));
typedef float f32x4 __attribute__((ext_vector_type(4)));
typedef unsigned int u32x4 __attribute__((ext_vector_type(4)));

__device__ __forceinline__ half8 as_half8(u32x4 v) { union { u32x4 u; half8 h; } x; x.u = v; return x.h; }

__device__ __forceinline__ float fsig(float x) {
  return __builtin_amdgcn_rcpf(1.f + __builtin_amdgcn_exp2f(-1.44269504f * x));
}
__device__ __forceinline__ float ftanh(float x) {
  float e = __builtin_amdgcn_exp2f(2.88539008f * x);   // e^{2x}
  return 1.f - 2.f * __builtin_amdgcn_rcpf(e + 1.f);
}

// ============ kernel A: fold embeddings through W_i -> PACKED proj tables ============
// packed index p = hh*4 + g  <->  standard col c = g*512 + hh
__global__ __launch_bounds__(256) void proj_tables(
    const float* __restrict__ boss_table, const float* __restrict__ hero_table,
    const float* __restrict__ W_i, const float* __restrict__ b_lstm,
    float* __restrict__ ws) {
  __shared__ float wrow[G_DIM];
  int r = blockIdx.x;
  bool useb = (r < BOSS_V);
  const float* tab = useb ? boss_table + r*D_EMB : hero_table + (r-BOSS_V)*D_EMB;
  const float* Wb  = useb ? W_i : W_i + (size_t)D_EMB*G_DIM;
  float* outp = useb ? ws + (size_t)r*G_DIM : ws + (WSB_HEROP/4) + (size_t)(r-BOSS_V)*G_DIM;
  int p0 = threadIdx.x * 8;
  int c[8]; float acc[8];
  #pragma unroll
  for (int j = 0; j < 8; ++j) {
    int p = p0 + j;
    c[j] = (p & 3)*512 + (p >> 2);
    acc[j] = useb ? b_lstm[c[j]] : 0.f;
  }
  for (int e = 0; e < D_EMB; ++e) {
    __syncthreads();
    for (int i = threadIdx.x; i < G_DIM; i += 256) wrow[i] = Wb[(size_t)e*G_DIM + i];
    __syncthreads();
    float te = tab[e];
    #pragma unroll
    for (int j = 0; j < 8; ++j) acc[j] = fmaf(te, wrow[c[j]], acc[j]);
  }
  #pragma unroll
  for (int j = 0; j < 8; ++j) outp[p0 + j] = acc[j];
}

// ============ kernel B: persistent MFMA LSTM + fused head ============
__global__ __launch_bounds__(NTHR, 1) void rudder_lstm(
    const int* __restrict__ boss_anim, const int* __restrict__ hero_anim,
    const float* __restrict__ continuous,
    const float* __restrict__ W_i, const float* __restrict__ W_h,
    const float* __restrict__ W1, const float* __restrict__ b1,
    const float* __restrict__ W2, const float* __restrict__ b2,
    char* __restrict__ wsb, float* __restrict__ out) {
  __shared__ __align__(16) char sh_h[16384];    // staged h_{t-1}: row b, 16B-word w at (w^(b&7))
  __shared__ __align__(16) char sh_w1[16384];   // W1 rows (z cols), same swizzle
  const int tid  = threadIdx.x;
  const int wave = tid >> 6;
  const int lane = tid & 63;
  const int b    = lane & 15;       // batch col / A row
  const int q    = lane >> 4;       // k-chunk / C-row group
  const int swz  = b & 7;
  const int wg   = blockIdx.x;
  const int cl   = wg & (NCL-1);
  const int wi   = wg >> 2;         // 0..15 within cluster
  const int B0   = cl * BG;
  const int hid0 = wi * 32;
  const int zc0  = wi * 16;

  const float* bossp = (const float*)(wsb + WSB_BOSSP);
  const float* herop = (const float*)(wsb + WSB_HEROP);
  char* hb = wsb + WSB_HBUF;
  int* flags_cl = (int*)(wsb + WSB_FLG) + cl*16;

  // ---- prologue 1: hoist W_h A-fragments into registers (static forever) ----
  u32x4 A0[16], A1[16];
  {
    const int Gc = (b & 3)*512 + hid0 + 8*wave + (b >> 2);   // tau=0; tau=1 -> +4
    #pragma unroll
    for (int s = 0; s < 16; ++s) {
      union { _Float16 h[8]; u32x4 u; } t0, t1;
      #pragma unroll
      for (int e = 0; e < 8; ++e) {
        int k = 32*s + q*8 + e;
        t0.h[e] = (_Float16)W_h[(size_t)k*G_DIM + Gc];
        t1.h[e] = (_Float16)W_h[(size_t)k*G_DIM + Gc + 4];
      }
      A0[s] = t0.u; A1[s] = t1.u;
    }
  }
  // ---- prologue 2: W1 slice -> LDS (rows r = z col zc0+r, swizzled) ----
  {
    int r = tid >> 4, cp16 = tid & 15;
    #pragma unroll
    for (int c2 = 0; c2 < 4; ++c2) {
      int w16 = cp16 + 16*c2;
      union { _Float16 h[8]; u32x4 u; } tw;
      #pragma unroll
      for (int e = 0; e < 8; ++e) tw.h[e] = (_Float16)W1[(size_t)(w16*8 + e)*ZC_TOT + zc0 + r];
      *(u32x4*)(sh_w1 + r*1024 + (((w16) ^ (r & 7)) << 4)) = tw.u;
    }
  }
  // ---- prologue 3: per-lane constants ----
  float Wc[3][2][4];
  #pragma unroll
  for (int c = 0; c < 3; ++c)
    #pragma unroll
    for (int ta = 0; ta < 2; ++ta)
      #pragma unroll
      for (int j = 0; j < 4; ++j)
        Wc[c][ta][j] = W_i[(size_t)(2*D_EMB + c)*G_DIM + j*512 + hid0 + 8*wave + 4*ta + q];
  float4 b1v = *(const float4*)(b1 + zc0 + 4*q);
  float4 W2v = *(const float4*)(W2 + zc0 + 4*q);
  float b2v = b2[0];
  float cst0 = 0.f, cst1 = 0.f;                    // c-state for (hh=8w+q, b) and (+4)
  const int pb0 = (hid0 + 8*wave + q)*4;           // packed xg base (tau0); tau1 = +16
  __syncthreads();

  for (int t = 0; t <= T_LEN; ++t) {
    const bool lstm  = (t < T_LEN);
    const bool head3 = (t > 0) && (wave == 3);

    // [A] xg gather (independent of h) — issue before the spin
    f32x4 x0 = {0.f,0.f,0.f,0.f}, x1 = {0.f,0.f,0.f,0.f};
    if (lstm) {
      const int row = (B0 + b)*T_LEN + t;
      int bi = min(max(boss_anim[row], 0), BOSS_V-1);
      int hj = min(max(hero_anim[row], 0), HERO_V-1);
      const float* bp = bossp + (size_t)bi*G_DIM + pb0;
      const float* hp = herop + (size_t)hj*G_DIM + pb0;
      float4 bv0 = *(const float4*)bp,      bv1 = *(const float4*)(bp + 16);
      float4 hv0 = *(const float4*)hp,      hv1 = *(const float4*)(hp + 16);
      const float* cp = continuous + (size_t)row*NCONT;
      float c0 = cp[0], c1 = cp[1], c2 = cp[2];
      float xb[8] = { bv0.x+hv0.x, bv0.y+hv0.y, bv0.z+hv0.z, bv0.w+hv0.w,
                      bv1.x+hv1.x, bv1.y+hv1.y, bv1.z+hv1.z, bv1.w+hv1.w };
      #pragma unroll
      for (int j = 0; j < 4; ++j) {
        x0[j] = xb[j]   + c0*Wc[0][0][j] + c1*Wc[1][0][j] + c2*Wc[2][0][j];
        x1[j] = xb[4+j] + c0*Wc[0][1][j] + c1*Wc[1][1][j] + c2*Wc[2][1][j];
      }
    }

    // spin: wave0 polls the cluster's 16 flags (single-writer, no RMW, LLC-coherent)
    if (t > 0 && wave == 0) {
      unsigned long long fa = (unsigned long long)(flags_cl + (lane & 15));
      int v;
      do {
        asm volatile("global_load_dword %0, %1, off sc0 sc1\n\ts_waitcnt vmcnt(0)"
                     : "=&v"(v) : "v"(fa) : "memory");
      } while (__any(v < t));
    }
    __syncthreads();  // SB0

    // stage h_{t-1}: 16 KB once per wg, coalesced GLOAD -> swizzled LDS
    {
      int r = tid >> 4, cp16 = tid & 15;
      unsigned long long src = (unsigned long long)(hb + ((t+1)&1)*65536 + (B0 + r)*1024 + cp16*16);
      u32x4 g0, g1, g2, g3;
      asm volatile("global_load_dwordx4 %0, %4, off sc0 sc1\n\t"
                   "global_load_dwordx4 %1, %4, off offset:256 sc0 sc1\n\t"
                   "global_load_dwordx4 %2, %4, off offset:512 sc0 sc1\n\t"
                   "global_load_dwordx4 %3, %4, off offset:768 sc0 sc1\n\t"
                   "s_waitcnt vmcnt(0)"
                   : "=&v"(g0), "=&v"(g1), "=&v"(g2), "=&v"(g3) : "v"(src) : "memory");
      char* dst = sh_h + r*1024;
      int m = r & 7;
      *(u32x4*)(dst + (((cp16 +  0) ^ m) << 4)) = g0;
      *(u32x4*)(dst + (((cp16 + 16) ^ m) << 4)) = g1;
      *(u32x4*)(dst + (((cp16 + 32) ^ m) << 4)) = g2;
      *(u32x4*)(dst + (((cp16 + 48) ^ m) << 4)) = g3;
    }
    __syncthreads();  // SB0b

    // D1 (all waves) + D2 head MFMA (wave3): B-frags shared from LDS
    f32x4 a00 = x0, a01 = {0.f,0.f,0.f,0.f};
    f32x4 a10 = x1, a11 = {0.f,0.f,0.f,0.f};
    f32x4 z = {0.f,0.f,0.f,0.f};
    const char* hrow = sh_h  + b*1024;
    const char* wrow = sh_w1 + b*1024;
    #pragma unroll
    for (int s = 0; s < 16; ++s) {
      int off = ((4*s + q) ^ swz) << 4;
      u32x4 Bf = *(const u32x4*)(hrow + off);
      if (lstm) {
        if (s & 1) {
          a01 = __builtin_amdgcn_mfma_f32_16x16x32_f16(as_half8(A0[s]), as_half8(Bf), a01, 0, 0, 0);
          a11 = __builtin_amdgcn_mfma_f32_16x16x32_f16(as_half8(A1[s]), as_half8(Bf), a11, 0, 0, 0);
        } else {
          a00 = __builtin_amdgcn_mfma_f32_16x16x32_f16(as_half8(A0[s]), as_half8(Bf), a00, 0, 0, 0);
          a10 = __builtin_amdgcn_mfma_f32_16x16x32_f16(as_half8(A1[s]), as_half8(Bf), a10, 0, 0, 0);
        }
      }
      if (head3) {
        u32x4 Af2 = *(const u32x4*)(wrow + off);
        z = __builtin_amdgcn_mfma_f32_16x16x32_f16(as_half8(Af2), as_half8(Bf), z, 0, 0, 0);
      }
    }

    // gates -> state update -> publish h_t (ALL lanes, 2 cells each, no shfl)
    if (lstm) {
      f32x4 g0 = a00 + a01;   // gates i,f,g,o for (hh=8w+q,   b)
      f32x4 g1 = a10 + a11;   // gates i,f,g,o for (hh=8w+4+q, b)
      cst0 = fsig(g0[1])*cst0 + fsig(g0[0])*ftanh(g0[2]);
      float hA = fsig(g0[3])*ftanh(cst0);
      cst1 = fsig(g1[1])*cst1 + fsig(g1[0])*ftanh(g1[2]);
      float hB = fsig(g1[3])*ftanh(cst1);
      union { _Float16 f; unsigned short u; } ua, ub;
      ua.f = (_Float16)hA; ub.f = (_Float16)hB;
      unsigned long long pd = (unsigned long long)(hb + (t&1)*65536)
                            + (unsigned)(((B0 + b)*512 + hid0 + 8*wave + q)*2);
      unsigned va = ua.u, vb = ub.u;
      asm volatile("global_store_short %0, %1, off sc0 sc1" :: "v"(pd), "v"(va) : "memory");
      asm volatile("global_store_short %0, %1, off offset:8 sc0 sc1" :: "v"(pd), "v"(vb) : "memory");
    }
    asm volatile("s_waitcnt vmcnt(0)" ::: "memory");   // h stores LLC-acked
    __syncthreads();  // SB1
    if (lstm && tid == 0) {
      unsigned long long fa = (unsigned long long)(flags_cl + wi);
      int val = t + 1;
      asm volatile("global_store_dword %0, %1, off sc0 sc1" :: "v"(fa), "v"(val) : "memory");
    }

    // head finalize for sample t-1 (wave3, off the inter-wg critical path)
    if (head3) {
      float sv = fmaxf(z[0] + b1v.x, 0.f)*W2v.x + fmaxf(z[1] + b1v.y, 0.f)*W2v.y
               + fmaxf(z[2] + b1v.z, 0.f)*W2v.z + fmaxf(z[3] + b1v.w, 0.f)*W2v.w;
      sv += __shfl_xor(sv, 16);
      sv += __shfl_xor(sv, 32);
      if (q == 0) {
        if (wi == 0) sv += b2v;
        atomicAdd(out + (size_t)(B0 + b)*T_LEN + (t-1), sv);
      }
    }
  }
}

// ============ launcher ============
extern "C" void kernel_launch(void* const* d_in, const int* in_sizes, int n_in,
                              void* d_out, int out_size, void* d_ws, size_t ws_size,
                              hipStream_t stream) {
  const int*   boss_anim  = (const int*)d_in[0];
  const int*   hero_anim  = (const int*)d_in[1];
  const float* continuous = (const float*)d_in[2];
  const float* boss_table = (const float*)d_in[3];
  const float* hero_table = (const float*)d_in[4];
  const float* W_i    = (const float*)d_in[5];
  const float* W_h    = (const float*)d_in[6];
  const float* b_lstm = (const float*)d_in[7];
  const float* W1     = (const float*)d_in[8];
  const float* b1     = (const float*)d_in[9];
  const float* W2     = (const float*)d_in[10];
  const float* b2     = (const float*)d_in[11];
  char*  wsb = (char*)d_ws;
  float* out = (float*)d_out;

  // zero output (atomicAdd target) + hbuf (both parities) + flags
  hipMemsetAsync(out, 0, (size_t)B_TOT*T_LEN*sizeof(float), stream);
  hipMemsetAsync(wsb + WSB_HBUF, 0, 2*B_TOT*H_DIM*2 + NCL*WPC*4, stream);

  proj_tables<<<BOSS_V + HERO_V, 256, 0, stream>>>(boss_table, hero_table, W_i, b_lstm, (float*)wsb);
  rudder_lstm<<<NCL*WPC, NTHR, 0, stream>>>(boss_anim, hero_anim, continuous,
      W_i, W_h, W1, b1, W2, b2, wsb, out);
}